// Round 21
// baseline (164.493 us; speedup 1.0000x reference)
//
#include <hip/hip_runtime.h>
#include <hip/hip_bf16.h>

typedef __attribute__((ext_vector_type(8))) short short8;
typedef __attribute__((ext_vector_type(16))) float f32x16;

namespace {
constexpr int B_ = 4, H_ = 8, L_ = 4096, D_ = 128, S_ = 1024;
constexpr int NTOK = B_ * H_ * L_;          // 131072
constexpr int SCAN_BLK = 256;               // 4 waves
constexpr int SCAN_TPW = 32, SCAN_TPB = 128;
constexpr int SCAN_GRID = NTOK / SCAN_TPB;  // 1024
constexpr int NCHUNK = 32;                  // 32 tiles of 32 codes
constexpr int RES_TPB = 128;
constexpr int RES_GRID = NTOK / RES_TPB;    // 1024
constexpr int PREP_GRID = H_ * S_ / 16;     // 512

// ws layout (bytes); no atomics anywhere -> per-block partial arrays
constexpr size_t WS_CHI   = 0;
constexpr size_t WS_CLO   = WS_CHI + 2ull * H_ * S_ * D_;
constexpr size_t WS_BN    = WS_CLO + 2ull * H_ * S_ * D_;
constexpr size_t WS_INV   = WS_BN + 4ull * H_ * S_;
constexpr size_t WS_BQ    = WS_INV + 4ull * H_ * S_;
constexpr size_t WS_CAND  = WS_BQ + 4ull * H_ * S_;          // NTOK u32
constexpr size_t WS_PREPP = WS_CAND + 4ull * NTOK;           // 512 doubles
constexpr size_t WS_RESC  = WS_PREPP + 8ull * PREP_GRID;     // 1024 doubles
constexpr size_t WS_REST  = WS_RESC + 8ull * RES_GRID;       // 1024 doubles
constexpr size_t WS_RESM  = WS_REST + 8ull * RES_GRID;       // 1024 ll
}

__device__ inline unsigned short bf_hi(float x) {
    __hip_bfloat16 h = __float2bfloat16(x);
    unsigned short u; __builtin_memcpy(&u, &h, 2); return u;
}
__device__ inline float bf_f(unsigned short u) {
    __hip_bfloat16 h; __builtin_memcpy(&h, &u, 2); return __bfloat162float(h);
}

// ---------------------------------------------------------------------------
// Prep: frag-major split bf16 of (-2*c_norm) for the 32x32x16 MFMA layout:
// tile st = s>>5 (32 codes), colp = s&31; lane j (=tid&15) owns d=[8j,8j+8):
// kc = j>>1 (K-chunk of 16), hi = j&1 (which K-half) ->
// short idx = (h*32+st)*4096 + kc*512 + (hi*32 + colp)*8 + (d&7).
// ---------------------------------------------------------------------------
__global__ __launch_bounds__(256) void vq_prep(
    const float* __restrict__ c_sum, const float* __restrict__ c_count,
    unsigned short* __restrict__ c_hi, unsigned short* __restrict__ c_lo,
    float* __restrict__ Bn, float* __restrict__ inv, float* __restrict__ Bq,
    double* __restrict__ prepPart) {
    const int tid = threadIdx.x;
    const int g = tid >> 4, j = tid & 15;
    const int row = blockIdx.x * 16 + g;
    const int h = row >> 10, s = row & 1023;
    const int st = s >> 5, colp = s & 31;

    float cnt = c_count[row];
    float iv = 1.0f / fmaxf(cnt, 0.01f);
    const float4* src = reinterpret_cast<const float4*>(c_sum + (size_t)row * D_) + 2 * j;
    float4 q0 = src[0], q1 = src[1];
    float e[8] = {q0.x, q0.y, q0.z, q0.w, q1.x, q1.y, q1.z, q1.w};
    short8 h8, l8;
    float sqn = 0.f, sqr = 0.f;
#pragma unroll
    for (int i = 0; i < 8; ++i) {
        float c = e[i] * iv;
        float t = -2.f * c;                    // exact scale+negate
        unsigned short hu = bf_hi(t);
        unsigned short lu = bf_hi(t - bf_f(hu));
        h8[i] = (short)hu; l8[i] = (short)lu;
        sqn += c * c; sqr += e[i] * e[i];
    }
    size_t base = (size_t)(h * 32 + st) * 4096 + (j >> 1) * 512 + ((j & 1) * 32 + colp) * 8;
    *reinterpret_cast<short8*>(c_hi + base) = h8;
    *reinterpret_cast<short8*>(c_lo + base) = l8;
#pragma unroll
    for (int o = 8; o; o >>= 1) { sqn += __shfl_xor(sqn, o); sqr += __shfl_xor(sqr, o); }

    __shared__ double sP[16];
    if (j == 0) {
        Bn[row] = sqn; inv[row] = iv; Bq[row] = iv * iv * sqr;
        sP[g] = (double)sqr + (double)cnt * (double)cnt;
    }
    __syncthreads();
    if (tid == 0) {
        double t = 0.0;
#pragma unroll
        for (int i = 0; i < 16; ++i) t += sP[i];
        prepPart[blockIdx.x] = t;
    }
}

#define MFMA32(a, b, c) __builtin_amdgcn_mfma_f32_32x32x16_bf16(a, b, c, 0, 0, 0)

// ---------------------------------------------------------------------------
// Scan: r20 skeleton, 32x32x16 MFMA (half the MFMA issue count). One 32-code
// tile per chunk; acc init = Bn (scores straight from MFMA); 24-deep chain.
// C/D: col=lane&31, row=(reg&3)+8*(reg>>2)+4*(lane>>5).
// ---------------------------------------------------------------------------
__global__ __launch_bounds__(SCAN_BLK) void vq_scan(
    const float* __restrict__ vecs,
    const unsigned short* __restrict__ c_hi, const unsigned short* __restrict__ c_lo,
    const float* __restrict__ Bn, unsigned int* __restrict__ cand) {
    const int tid = threadIdx.x;
    const int wave = tid >> 6, lane = tid & 63;
    const int col = lane & 31, khalf = lane >> 5;
    const int blk = ((blockIdx.x & 7) << 7) | (blockIdx.x >> 3);
    const int t0b = blk * SCAN_TPB;
    const int h = (t0b >> 12) & 7;
    const int t0w = t0b + wave * SCAN_TPW;

    __shared__ short sB[2][2][4096];

    // ---- A fragments: row = lane&31 (token), k = khalf*8 + j per K-chunk ----
    short8 ah[8], al[8];
#pragma unroll
    for (int kc = 0; kc < 8; ++kc) {
        const float* vp = vecs + (size_t)(t0w + col) * D_ + kc * 16 + khalf * 8;
        float4 q0 = *reinterpret_cast<const float4*>(vp);
        float4 q1 = *reinterpret_cast<const float4*>(vp + 4);
        float f[8] = {q0.x, q0.y, q0.z, q0.w, q1.x, q1.y, q1.z, q1.w};
        short8 h8, l8;
#pragma unroll
        for (int i = 0; i < 8; ++i) {
            unsigned short hu = bf_hi(f[i]);
            unsigned short lu = bf_hi(f[i] - bf_f(hu));
            h8[i] = (short)hu; l8[i] = (short)lu;
        }
        ah[kc] = h8; al[kc] = l8;
    }

    const float* Bnh = Bn + h * S_;
    const float4* ghi = reinterpret_cast<const float4*>(c_hi) + (size_t)h * 16384;
    const float4* glo = reinterpret_cast<const float4*>(c_lo) + (size_t)h * 16384;

    float4 sg0 = ghi[tid], sg1 = ghi[256 + tid], sg2 = glo[tid], sg3 = glo[256 + tid];
    {
        float4* pH = reinterpret_cast<float4*>(&sB[0][0][0]);
        float4* pL = reinterpret_cast<float4*>(&sB[0][1][0]);
        pH[tid] = sg0; pH[256 + tid] = sg1;
        pL[tid] = sg2; pL[256 + tid] = sg3;
    }
    __syncthreads();

    float m1[16], m2[16];
#pragma unroll
    for (int i = 0; i < 16; ++i) { m1[i] = INFINITY; m2[i] = INFINITY; }

#pragma unroll 1
    for (int c = 0; c < NCHUNK; ++c) {
        const int cur = c & 1, nxt = cur ^ 1;
        const float bsc = Bnh[c * 32 + col];   // score base for this lane's col
        if (c + 1 < NCHUNK) {
            const float4* gh = ghi + (size_t)(c + 1) * 512;
            const float4* gl = glo + (size_t)(c + 1) * 512;
            sg0 = gh[tid]; sg1 = gh[256 + tid]; sg2 = gl[tid]; sg3 = gl[256 + tid];
        }
        short8 bh[8], bl[8];
#pragma unroll
        for (int kc = 0; kc < 8; ++kc) {
            bh[kc] = *reinterpret_cast<const short8*>(&sB[cur][0][kc * 512 + lane * 8]);
            bl[kc] = *reinterpret_cast<const short8*>(&sB[cur][1][kc * 512 + lane * 8]);
        }
        // acc init = Bn[col]; 24 MFMA accumulate (hi.hi, hi.lo, lo.hi)
        f32x16 acc;
#pragma unroll
        for (int i = 0; i < 16; ++i) acc[i] = bsc;
#pragma unroll
        for (int kc = 0; kc < 8; ++kc) acc = MFMA32(ah[kc], bh[kc], acc);
#pragma unroll
        for (int kc = 0; kc < 8; ++kc) acc = MFMA32(ah[kc], bl[kc], acc);
#pragma unroll
        for (int kc = 0; kc < 8; ++kc) acc = MFMA32(al[kc], bh[kc], acc);
        // top-2 update, tile index packed into low 6 mantissa bits
#pragma unroll
        for (int i = 0; i < 16; ++i) {
            float pk = __uint_as_float((__float_as_uint(acc[i]) & 0xFFFFFFC0u) | (unsigned)c);
            bool cc = pk < m1[i];
            m2[i] = cc ? m1[i] : fminf(pk, m2[i]);
            m1[i] = cc ? pk : m1[i];
        }
        if (c + 1 < NCHUNK) {
            float4* pH = reinterpret_cast<float4*>(&sB[nxt][0][0]);
            float4* pL = reinterpret_cast<float4*>(&sB[nxt][1][0]);
            pH[tid] = sg0; pH[256 + tid] = sg1;
            pL[tid] = sg2; pL[256 + tid] = sg3;
        }
        __syncthreads();
    }

    // ---- decode packed top-2, butterfly merge across the 32 cols ----
#pragma unroll
    for (int i = 0; i < 16; ++i) {
        float a1v = m1[i], a2v = m2[i];
        int x1 = (int)((__float_as_uint(a1v) & 63u) << 5) | col;   // s = tile*32+col
        int x2 = (int)((__float_as_uint(a2v) & 63u) << 5) | col;
#pragma unroll
        for (int mask = 1; mask < 32; mask <<= 1) {
            float b1 = __shfl_xor(a1v, mask), b2 = __shfl_xor(a2v, mask);
            int y1 = __shfl_xor(x1, mask), y2 = __shfl_xor(x2, mask);
            bool sw = (b1 < a1v) || (b1 == a1v && y1 < x1);
            float w1 = sw ? b1 : a1v; int wi1 = sw ? y1 : x1;
            float r  = sw ? a1v : b1; int ri  = sw ? x1 : y1;
            float w2 = sw ? b2 : a2v; int wi2 = sw ? y2 : x2;
            bool s2 = (r < w2) || (r == w2 && ri < wi2);
            a1v = w1; x1 = wi1;
            a2v = s2 ? r : w2; x2 = s2 ? ri : wi2;
        }
        if (col == 0) {
            int rrow = (i & 3) + 8 * (i >> 2) + 4 * khalf;
            cand[t0w + rrow] = (unsigned)x1 | ((unsigned)x2 << 10);
        }
    }
}

// ---------------------------------------------------------------------------
// Rescore: 16-lane cooperative dots (r18-proven), partials to ws.
// ---------------------------------------------------------------------------
__global__ __launch_bounds__(256) void vq_rescore(
    const float* __restrict__ vecs, const float* __restrict__ c_sum,
    const float* __restrict__ c_count, const int* __restrict__ lmask,
    const float* __restrict__ inv_a, const float* __restrict__ Bq,
    const unsigned int* __restrict__ cand,
    double* __restrict__ resC, double* __restrict__ resT,
    long long* __restrict__ resM,
    float* __restrict__ out_hat, float* __restrict__ out_z) {
    const int tid = threadIdx.x;
    const int lane = tid & 63;
    const int g = tid >> 4, j = tid & 15;
    const int blk = ((blockIdx.x & 7) << 7) | (blockIdx.x >> 3);
    const int t0 = blk * RES_TPB;
    const int h = (t0 >> 12) & 7;
    const int b = t0 >> 15;

    __shared__ float sDot[RES_TPB][2];
    __shared__ float sVs[RES_TPB];
    __shared__ int sZ[RES_TPB];
    __shared__ double sC[4], sT[4];
    __shared__ long long sM[4];

#pragma unroll 1
    for (int r = 0; r < 16; ++r) {
        const int p = r * 16 + g;
        const int lt = p >> 1, slot = p & 1;
        const unsigned int cw = cand[t0 + lt];
        const int cidx = slot ? (int)((cw >> 10) & 1023u) : (int)(cw & 1023u);
        const float4* vp = reinterpret_cast<const float4*>(vecs + (size_t)(t0 + lt) * D_);
        const float4* cp = reinterpret_cast<const float4*>(c_sum + ((size_t)h * S_ + cidx) * D_);
        float4 qa = vp[j], qb = vp[16 + j];
        float4 pa = cp[j], pb = cp[16 + j];
        float dot = qa.x * pa.x + qa.y * pa.y + qa.z * pa.z + qa.w * pa.w
                  + qb.x * pb.x + qb.y * pb.y + qb.z * pb.z + qb.w * pb.w;
        float vs = qa.x * qa.x + qa.y * qa.y + qa.z * qa.z + qa.w * qa.w
                 + qb.x * qb.x + qb.y * qb.y + qb.z * qb.z + qb.w * qb.w;
#pragma unroll
        for (int o = 8; o; o >>= 1) { dot += __shfl_xor(dot, o); vs += __shfl_xor(vs, o); }
        if (j == 0) {
            sDot[lt][slot] = dot;
            if (slot == 0) sVs[lt] = vs;
        }
    }
    __syncthreads();

    double commit = 0.0, tokc = 0.0;
    long long mcnt = 0;
    if (tid < RES_TPB) {
        const int lt = tid, tok = t0 + lt;
        const unsigned int cw = cand[tok];
        const int c0 = (int)(cw & 1023u), c1 = (int)((cw >> 10) & 1023u);
        const float dot0 = sDot[lt][0], dot1 = sDot[lt][1], vs = sVs[lt];
        const float dist0 = vs - 2.f * (inv_a[h * S_ + c0] * dot0) + Bq[h * S_ + c0];
        const float dist1 = vs - 2.f * (inv_a[h * S_ + c1] * dot1) + Bq[h * S_ + c1];
        const bool w0 = (dist0 < dist1) || (dist0 == dist1 && c0 < c1);
        const float dwin = w0 ? dist0 : dist1;
        const int zwin = w0 ? c0 : c1;
        const float dotw = w0 ? dot0 : dot1;
        out_z[tok] = (float)zwin;
        sZ[lt] = zwin;
        const int lm = lmask[b * L_ + (tok & (L_ - 1))];
        const float mask = (float)lm;
        commit = (double)(mask * fmaxf(dwin, 0.f));
        tokc = (double)mask * ((double)dotw + (double)c_count[h * S_ + zwin]);
        if (h == 0) mcnt = lm;
    }
#pragma unroll
    for (int o = 32; o; o >>= 1) {
        commit += __shfl_down(commit, o);
        tokc   += __shfl_down(tokc, o);
        mcnt   += __shfl_down(mcnt, o);
    }
    const int w = tid >> 6;
    if (lane == 0) { sC[w] = commit; sT[w] = tokc; sM[w] = mcnt; }
    __syncthreads();
    if (tid == 0) {
        resC[blockIdx.x] = sC[0] + sC[1] + sC[2] + sC[3];
        resT[blockIdx.x] = sT[0] + sT[1] + sT[2] + sT[3];
        resM[blockIdx.x] = sM[0] + sM[1] + sM[2] + sM[3];
    }

    const int hw = tid >> 5, hl = tid & 31;
#pragma unroll
    for (int r0 = 0; r0 < 16; ++r0) {
        int r = r0 * 8 + hw;
        int z = sZ[r];
        float ivz = inv_a[h * S_ + z];
        float4 p = reinterpret_cast<const float4*>(c_sum + ((size_t)h * S_ + z) * D_)[hl];
        float4 o; o.x = p.x * ivz; o.y = p.y * ivz; o.z = p.z * ivz; o.w = p.w * ivz;
        reinterpret_cast<float4*>(out_hat + (size_t)(t0 + r) * D_)[hl] = o;
    }
}

__global__ __launch_bounds__(256) void vq_final(
    const double* __restrict__ prepPart, const double* __restrict__ resC,
    const double* __restrict__ resT, const long long* __restrict__ resM,
    float* __restrict__ out_sc) {
    const int tid = threadIdx.x;
    double cs = 0.0, cm = 0.0, tk = 0.0;
    long long mk = 0;
    for (int i = tid; i < PREP_GRID; i += 256) cs += prepPart[i];
    for (int i = tid; i < RES_GRID; i += 256) { cm += resC[i]; tk += resT[i]; mk += resM[i]; }
    __shared__ double aC[4], aM[4], aT[4];
    __shared__ long long aK[4];
#pragma unroll
    for (int o = 32; o; o >>= 1) {
        cs += __shfl_down(cs, o);
        cm += __shfl_down(cm, o);
        tk += __shfl_down(tk, o);
        mk += __shfl_down(mk, o);
    }
    const int w = tid >> 6;
    if ((tid & 63) == 0) { aC[w] = cs; aM[w] = cm; aT[w] = tk; aK[w] = mk; }
    __syncthreads();
    if (tid == 0) {
        double CS = aC[0] + aC[1] + aC[2] + aC[3];
        double CM = aM[0] + aM[1] + aM[2] + aM[3];
        double TK = aT[0] + aT[1] + aT[2] + aT[3];
        double NT = (double)(aK[0] + aK[1] + aK[2] + aK[3]);
        if (NT < 1.0) NT = 1.0;
        out_sc[0] = (float)(CM / ((double)H_ * NT));
        out_sc[1] = (float)(0.01 * (CS - TK));
    }
}

extern "C" void kernel_launch(void* const* d_in, const int* in_sizes, int n_in,
                              void* d_out, int out_size, void* d_ws, size_t ws_size,
                              hipStream_t stream) {
    const float* vecs    = (const float*)d_in[0];
    const float* c_sum   = (const float*)d_in[1];
    const float* c_count = (const float*)d_in[2];
    const int*   lmask   = (const int*)d_in[3];

    char* ws = (char*)d_ws;
    unsigned short* c_hi = (unsigned short*)(ws + WS_CHI);
    unsigned short* c_lo = (unsigned short*)(ws + WS_CLO);
    float* Bn  = (float*)(ws + WS_BN);
    float* inv = (float*)(ws + WS_INV);
    float* Bq  = (float*)(ws + WS_BQ);
    unsigned int* cand = (unsigned int*)(ws + WS_CAND);
    double* prepPart = (double*)(ws + WS_PREPP);
    double* resC = (double*)(ws + WS_RESC);
    double* resT = (double*)(ws + WS_REST);
    long long* resM = (long long*)(ws + WS_RESM);

    float* out = (float*)d_out;
    float* out_sc = out + (size_t)out_size - 2;
    float* out_z  = out_sc - (size_t)NTOK;

    vq_prep<<<PREP_GRID, 256, 0, stream>>>(c_sum, c_count, c_hi, c_lo, Bn, inv, Bq, prepPart);
    vq_scan<<<SCAN_GRID, SCAN_BLK, 0, stream>>>(vecs, c_hi, c_lo, Bn, cand);
    vq_rescore<<<RES_GRID, 256, 0, stream>>>(vecs, c_sum, c_count, lmask, inv, Bq,
                                             cand, resC, resT, resM, out, out_z);
    vq_final<<<1, 256, 0, stream>>>(prepPart, resC, resT, resM, out_sc);
}

// Round 22
// 144.326 us; speedup vs baseline: 1.1397x; 1.1397x over previous
//
#include <hip/hip_runtime.h>
#include <hip/hip_bf16.h>

typedef __attribute__((ext_vector_type(8))) short short8;
typedef __attribute__((ext_vector_type(4))) float f32x4;

namespace {
constexpr int B_ = 4, H_ = 8, L_ = 4096, D_ = 128, S_ = 1024;
constexpr int NTOK = B_ * H_ * L_;          // 131072
constexpr int SCAN_BLK = 256;               // 4 waves
constexpr int SCAN_TPW = 32, SCAN_TPB = 128;
constexpr int SCAN_GRID = NTOK / SCAN_TPB;  // 1024
constexpr int NCHUNK = 32;                  // 2 s-tiles (32 codes) per chunk
constexpr int RES_TPB = 128;
constexpr int RES_GRID = NTOK / RES_TPB;    // 1024
constexpr int PREP_GRID = H_ * S_ / 16;     // 512

// ws layout (bytes); no atomics anywhere -> per-block partial arrays
constexpr size_t WS_CHI   = 0;
constexpr size_t WS_CLO   = WS_CHI + 2ull * H_ * S_ * D_;
constexpr size_t WS_BN    = WS_CLO + 2ull * H_ * S_ * D_;
constexpr size_t WS_INV   = WS_BN + 4ull * H_ * S_;
constexpr size_t WS_BQ    = WS_INV + 4ull * H_ * S_;
constexpr size_t WS_CAND  = WS_BQ + 4ull * H_ * S_;          // NTOK u32
constexpr size_t WS_PREPP = WS_CAND + 4ull * NTOK;           // 512 doubles
constexpr size_t WS_RESC  = WS_PREPP + 8ull * PREP_GRID;     // 1024 doubles
constexpr size_t WS_REST  = WS_RESC + 8ull * RES_GRID;       // 1024 doubles
constexpr size_t WS_RESM  = WS_REST + 8ull * RES_GRID;       // 1024 ll
}

__device__ inline unsigned short bf_hi(float x) {
    __hip_bfloat16 h = __float2bfloat16(x);
    unsigned short u; __builtin_memcpy(&u, &h, 2); return u;
}
__device__ inline float bf_f(unsigned short u) {
    __hip_bfloat16 h; __builtin_memcpy(&h, &u, 2); return __bfloat162float(h);
}

// ---------------------------------------------------------------------------
// Prep: 16 lanes per (h,s) row -> frag-major split bf16 of (-2*c_norm).
// (-2 folded into the codebook: MFMA then emits |c|^2 - 2 v.c directly
// when the accumulator is initialized with Bn.)
// ---------------------------------------------------------------------------
__global__ __launch_bounds__(256) void vq_prep(
    const float* __restrict__ c_sum, const float* __restrict__ c_count,
    unsigned short* __restrict__ c_hi, unsigned short* __restrict__ c_lo,
    float* __restrict__ Bn, float* __restrict__ inv, float* __restrict__ Bq,
    double* __restrict__ prepPart) {
    const int tid = threadIdx.x;
    const int g = tid >> 4, j = tid & 15;
    const int row = blockIdx.x * 16 + g;
    const int h = row >> 10, s = row & 1023;
    const int st = s >> 4, colp = s & 15;

    float cnt = c_count[row];
    float iv = 1.0f / fmaxf(cnt, 0.01f);
    const float4* src = reinterpret_cast<const float4*>(c_sum + (size_t)row * D_) + 2 * j;
    float4 q0 = src[0], q1 = src[1];
    float e[8] = {q0.x, q0.y, q0.z, q0.w, q1.x, q1.y, q1.z, q1.w};
    short8 h8, l8;
    float sqn = 0.f, sqr = 0.f;
#pragma unroll
    for (int i = 0; i < 8; ++i) {
        float c = e[i] * iv;
        float t = -2.f * c;                    // exact scale+negate
        unsigned short hu = bf_hi(t);
        unsigned short lu = bf_hi(t - bf_f(hu));
        h8[i] = (short)hu; l8[i] = (short)lu;
        sqn += c * c; sqr += e[i] * e[i];
    }
    size_t base = (size_t)(h * 64 + st) * 2048 + (j >> 2) * 512 + ((j & 3) * 16 + colp) * 8;
    *reinterpret_cast<short8*>(c_hi + base) = h8;
    *reinterpret_cast<short8*>(c_lo + base) = l8;
#pragma unroll
    for (int o = 8; o; o >>= 1) { sqn += __shfl_xor(sqn, o); sqr += __shfl_xor(sqr, o); }

    __shared__ double sP[16];
    if (j == 0) {
        Bn[row] = sqn; inv[row] = iv; Bq[row] = iv * iv * sqr;
        sP[g] = (double)sqr + (double)cnt * (double)cnt;
    }
    __syncthreads();
    if (tid == 0) {
        double t = 0.0;
#pragma unroll
        for (int i = 0; i < 16; ++i) t += sP[i];
        prepPart[blockIdx.x] = t;
    }
}

#define MFMA(a, b, c) __builtin_amdgcn_mfma_f32_16x16x32_bf16(a, b, c, 0, 0, 0)

// ---------------------------------------------------------------------------
// Scan: r20 skeleton (proven 129us): 4 waves, 2-tile chunks, 32KB LDS dbuf,
// acc init = Bn (scores straight from MFMA), 2 independent 12-deep chains.
// Top-2 update via min/max identity (m2=min(m2,max(m1,pk)); m1=min(m1,pk)) --
// provably identical selection, 1 fewer VALU op per score.
// ---------------------------------------------------------------------------
__global__ __launch_bounds__(SCAN_BLK) void vq_scan(
    const float* __restrict__ vecs,
    const unsigned short* __restrict__ c_hi, const unsigned short* __restrict__ c_lo,
    const float* __restrict__ Bn, unsigned int* __restrict__ cand) {
    const int tid = threadIdx.x;
    const int wave = tid >> 6, lane = tid & 63;
    const int col = lane & 15, kg = lane >> 4;
    const int blk = ((blockIdx.x & 7) << 7) | (blockIdx.x >> 3);
    const int t0b = blk * SCAN_TPB;
    const int h = (t0b >> 12) & 7;
    const int t0w = t0b + wave * SCAN_TPW;

    __shared__ short sB[2][2][4096];

    short8 ah[2][4], al[2][4];
#pragma unroll
    for (int mt = 0; mt < 2; ++mt)
#pragma unroll
        for (int ck = 0; ck < 4; ++ck) {
            const float* vp = vecs + (size_t)(t0w + mt * 16 + col) * D_ + ck * 32 + kg * 8;
            float4 q0 = *reinterpret_cast<const float4*>(vp);
            float4 q1 = *reinterpret_cast<const float4*>(vp + 4);
            float f[8] = {q0.x, q0.y, q0.z, q0.w, q1.x, q1.y, q1.z, q1.w};
            short8 h8, l8;
#pragma unroll
            for (int i = 0; i < 8; ++i) {
                unsigned short hu = bf_hi(f[i]);
                unsigned short lu = bf_hi(f[i] - bf_f(hu));
                h8[i] = (short)hu; l8[i] = (short)lu;
            }
            ah[mt][ck] = h8; al[mt][ck] = l8;
        }

    const float* Bnh = Bn + h * S_;
    const float4* ghi = reinterpret_cast<const float4*>(c_hi) + (size_t)h * 16384;
    const float4* glo = reinterpret_cast<const float4*>(c_lo) + (size_t)h * 16384;

    float4 sg0 = ghi[tid], sg1 = ghi[256 + tid], sg2 = glo[tid], sg3 = glo[256 + tid];
    {
        float4* pH = reinterpret_cast<float4*>(&sB[0][0][0]);
        float4* pL = reinterpret_cast<float4*>(&sB[0][1][0]);
        pH[tid] = sg0; pH[256 + tid] = sg1;
        pL[tid] = sg2; pL[256 + tid] = sg3;
    }
    __syncthreads();

    float m1[2][4], m2[2][4];
#pragma unroll
    for (int mt = 0; mt < 2; ++mt)
#pragma unroll
        for (int i = 0; i < 4; ++i) { m1[mt][i] = INFINITY; m2[mt][i] = INFINITY; }

#pragma unroll 1
    for (int c = 0; c < NCHUNK; ++c) {
        const int cur = c & 1, nxt = cur ^ 1;
        // bsc for both tiles of this chunk, issued before ds_reads
        float bsc0 = Bnh[(2 * c + 0) * 16 + col];
        float bsc1 = Bnh[(2 * c + 1) * 16 + col];
        if (c + 1 < NCHUNK) {
            const float4* gh = ghi + (size_t)(c + 1) * 512;
            const float4* gl = glo + (size_t)(c + 1) * 512;
            sg0 = gh[tid]; sg1 = gh[256 + tid]; sg2 = gl[tid]; sg3 = gl[256 + tid];
        }
#pragma unroll
        for (int tl = 0; tl < 2; ++tl) {
            const int st = c * 2 + tl;
            const float bsc = tl ? bsc1 : bsc0;
            short8 bh[4], bl[4];
#pragma unroll
            for (int ck = 0; ck < 4; ++ck) {
                bh[ck] = *reinterpret_cast<const short8*>(&sB[cur][0][tl * 2048 + ck * 512 + lane * 8]);
                bl[ck] = *reinterpret_cast<const short8*>(&sB[cur][1][tl * 2048 + ck * 512 + lane * 8]);
            }
            // acc init = Bn; 2 independent 12-deep same-acc MFMA chains
            f32x4 pa0 = {bsc, bsc, bsc, bsc};
            f32x4 pa1 = {bsc, bsc, bsc, bsc};
#pragma unroll
            for (int ck = 0; ck < 4; ++ck) {
                pa0 = MFMA(ah[0][ck], bh[ck], pa0);
                pa1 = MFMA(ah[1][ck], bh[ck], pa1);
            }
#pragma unroll
            for (int ck = 0; ck < 4; ++ck) {
                pa0 = MFMA(ah[0][ck], bl[ck], pa0);
                pa1 = MFMA(ah[1][ck], bl[ck], pa1);
            }
#pragma unroll
            for (int ck = 0; ck < 4; ++ck) {
                pa0 = MFMA(al[0][ck], bh[ck], pa0);
                pa1 = MFMA(al[1][ck], bh[ck], pa1);
            }
#pragma unroll
            for (int i = 0; i < 4; ++i) {
                float pk = __uint_as_float((__float_as_uint(pa0[i]) & 0xFFFFFFC0u) | (unsigned)st);
                m2[0][i] = fminf(m2[0][i], fmaxf(m1[0][i], pk));
                m1[0][i] = fminf(m1[0][i], pk);
                pk = __uint_as_float((__float_as_uint(pa1[i]) & 0xFFFFFFC0u) | (unsigned)st);
                m2[1][i] = fminf(m2[1][i], fmaxf(m1[1][i], pk));
                m1[1][i] = fminf(m1[1][i], pk);
            }
        }
        if (c + 1 < NCHUNK) {
            float4* pH = reinterpret_cast<float4*>(&sB[nxt][0][0]);
            float4* pL = reinterpret_cast<float4*>(&sB[nxt][1][0]);
            pH[tid] = sg0; pH[256 + tid] = sg1;
            pL[tid] = sg2; pL[256 + tid] = sg3;
        }
        __syncthreads();
    }

#pragma unroll
    for (int mt = 0; mt < 2; ++mt)
#pragma unroll
        for (int i = 0; i < 4; ++i) {
            float a1v = m1[mt][i], a2v = m2[mt][i];
            int x1 = (int)((__float_as_uint(a1v) & 63u) << 4) | col;
            int x2 = (int)((__float_as_uint(a2v) & 63u) << 4) | col;
#pragma unroll
            for (int mask = 1; mask < 16; mask <<= 1) {
                float b1 = __shfl_xor(a1v, mask), b2 = __shfl_xor(a2v, mask);
                int y1 = __shfl_xor(x1, mask), y2 = __shfl_xor(x2, mask);
                bool sw = (b1 < a1v) || (b1 == a1v && y1 < x1);
                float w1 = sw ? b1 : a1v; int wi1 = sw ? y1 : x1;
                float r  = sw ? a1v : b1; int ri  = sw ? x1 : y1;
                float w2 = sw ? b2 : a2v; int wi2 = sw ? y2 : x2;
                bool s2 = (r < w2) || (r == w2 && ri < wi2);
                a1v = w1; x1 = wi1;
                a2v = s2 ? r : w2; x2 = s2 ? ri : wi2;
            }
            if (col == 0) {
                int lt = mt * 16 + kg * 4 + i;
                cand[t0w + lt] = (unsigned)x1 | ((unsigned)x2 << 10);
            }
        }
}

// ---------------------------------------------------------------------------
// Rescore: 16-lane cooperative dots (r18-proven), partials to ws.
// ---------------------------------------------------------------------------
__global__ __launch_bounds__(256) void vq_rescore(
    const float* __restrict__ vecs, const float* __restrict__ c_sum,
    const float* __restrict__ c_count, const int* __restrict__ lmask,
    const float* __restrict__ inv_a, const float* __restrict__ Bq,
    const unsigned int* __restrict__ cand,
    double* __restrict__ resC, double* __restrict__ resT,
    long long* __restrict__ resM,
    float* __restrict__ out_hat, float* __restrict__ out_z) {
    const int tid = threadIdx.x;
    const int lane = tid & 63;
    const int g = tid >> 4, j = tid & 15;
    const int blk = ((blockIdx.x & 7) << 7) | (blockIdx.x >> 3);
    const int t0 = blk * RES_TPB;
    const int h = (t0 >> 12) & 7;
    const int b = t0 >> 15;

    __shared__ float sDot[RES_TPB][2];
    __shared__ float sVs[RES_TPB];
    __shared__ int sZ[RES_TPB];
    __shared__ double sC[4], sT[4];
    __shared__ long long sM[4];

#pragma unroll 1
    for (int r = 0; r < 16; ++r) {
        const int p = r * 16 + g;
        const int lt = p >> 1, slot = p & 1;
        const unsigned int cw = cand[t0 + lt];
        const int cidx = slot ? (int)((cw >> 10) & 1023u) : (int)(cw & 1023u);
        const float4* vp = reinterpret_cast<const float4*>(vecs + (size_t)(t0 + lt) * D_);
        const float4* cp = reinterpret_cast<const float4*>(c_sum + ((size_t)h * S_ + cidx) * D_);
        float4 qa = vp[j], qb = vp[16 + j];
        float4 pa = cp[j], pb = cp[16 + j];
        float dot = qa.x * pa.x + qa.y * pa.y + qa.z * pa.z + qa.w * pa.w
                  + qb.x * pb.x + qb.y * pb.y + qb.z * pb.z + qb.w * pb.w;
        float vs = qa.x * qa.x + qa.y * qa.y + qa.z * qa.z + qa.w * qa.w
                 + qb.x * qb.x + qb.y * qb.y + qb.z * qb.z + qb.w * qb.w;
#pragma unroll
        for (int o = 8; o; o >>= 1) { dot += __shfl_xor(dot, o); vs += __shfl_xor(vs, o); }
        if (j == 0) {
            sDot[lt][slot] = dot;
            if (slot == 0) sVs[lt] = vs;
        }
    }
    __syncthreads();

    double commit = 0.0, tokc = 0.0;
    long long mcnt = 0;
    if (tid < RES_TPB) {
        const int lt = tid, tok = t0 + lt;
        const unsigned int cw = cand[tok];
        const int c0 = (int)(cw & 1023u), c1 = (int)((cw >> 10) & 1023u);
        const float dot0 = sDot[lt][0], dot1 = sDot[lt][1], vs = sVs[lt];
        const float dist0 = vs - 2.f * (inv_a[h * S_ + c0] * dot0) + Bq[h * S_ + c0];
        const float dist1 = vs - 2.f * (inv_a[h * S_ + c1] * dot1) + Bq[h * S_ + c1];
        const bool w0 = (dist0 < dist1) || (dist0 == dist1 && c0 < c1);
        const float dwin = w0 ? dist0 : dist1;
        const int zwin = w0 ? c0 : c1;
        const float dotw = w0 ? dot0 : dot1;
        out_z[tok] = (float)zwin;
        sZ[lt] = zwin;
        const int lm = lmask[b * L_ + (tok & (L_ - 1))];
        const float mask = (float)lm;
        commit = (double)(mask * fmaxf(dwin, 0.f));
        tokc = (double)mask * ((double)dotw + (double)c_count[h * S_ + zwin]);
        if (h == 0) mcnt = lm;
    }
#pragma unroll
    for (int o = 32; o; o >>= 1) {
        commit += __shfl_down(commit, o);
        tokc   += __shfl_down(tokc, o);
        mcnt   += __shfl_down(mcnt, o);
    }
    const int w = tid >> 6;
    if (lane == 0) { sC[w] = commit; sT[w] = tokc; sM[w] = mcnt; }
    __syncthreads();
    if (tid == 0) {
        resC[blockIdx.x] = sC[0] + sC[1] + sC[2] + sC[3];
        resT[blockIdx.x] = sT[0] + sT[1] + sT[2] + sT[3];
        resM[blockIdx.x] = sM[0] + sM[1] + sM[2] + sM[3];
    }

    const int hw = tid >> 5, hl = tid & 31;
#pragma unroll
    for (int r0 = 0; r0 < 16; ++r0) {
        int r = r0 * 8 + hw;
        int z = sZ[r];
        float ivz = inv_a[h * S_ + z];
        float4 p = reinterpret_cast<const float4*>(c_sum + ((size_t)h * S_ + z) * D_)[hl];
        float4 o; o.x = p.x * ivz; o.y = p.y * ivz; o.z = p.z * ivz; o.w = p.w * ivz;
        reinterpret_cast<float4*>(out_hat + (size_t)(t0 + r) * D_)[hl] = o;
    }
}

__global__ __launch_bounds__(256) void vq_final(
    const double* __restrict__ prepPart, const double* __restrict__ resC,
    const double* __restrict__ resT, const long long* __restrict__ resM,
    float* __restrict__ out_sc) {
    const int tid = threadIdx.x;
    double cs = 0.0, cm = 0.0, tk = 0.0;
    long long mk = 0;
    for (int i = tid; i < PREP_GRID; i += 256) cs += prepPart[i];
    for (int i = tid; i < RES_GRID; i += 256) { cm += resC[i]; tk += resT[i]; mk += resM[i]; }
    __shared__ double aC[4], aM[4], aT[4];
    __shared__ long long aK[4];
#pragma unroll
    for (int o = 32; o; o >>= 1) {
        cs += __shfl_down(cs, o);
        cm += __shfl_down(cm, o);
        tk += __shfl_down(tk, o);
        mk += __shfl_down(mk, o);
    }
    const int w = tid >> 6;
    if ((tid & 63) == 0) { aC[w] = cs; aM[w] = cm; aT[w] = tk; aK[w] = mk; }
    __syncthreads();
    if (tid == 0) {
        double CS = aC[0] + aC[1] + aC[2] + aC[3];
        double CM = aM[0] + aM[1] + aM[2] + aM[3];
        double TK = aT[0] + aT[1] + aT[2] + aT[3];
        double NT = (double)(aK[0] + aK[1] + aK[2] + aK[3]);
        if (NT < 1.0) NT = 1.0;
        out_sc[0] = (float)(CM / ((double)H_ * NT));
        out_sc[1] = (float)(0.01 * (CS - TK));
    }
}

extern "C" void kernel_launch(void* const* d_in, const int* in_sizes, int n_in,
                              void* d_out, int out_size, void* d_ws, size_t ws_size,
                              hipStream_t stream) {
    const float* vecs    = (const float*)d_in[0];
    const float* c_sum   = (const float*)d_in[1];
    const float* c_count = (const float*)d_in[2];
    const int*   lmask   = (const int*)d_in[3];

    char* ws = (char*)d_ws;
    unsigned short* c_hi = (unsigned short*)(ws + WS_CHI);
    unsigned short* c_lo = (unsigned short*)(ws + WS_CLO);
    float* Bn  = (float*)(ws + WS_BN);
    float* inv = (float*)(ws + WS_INV);
    float* Bq  = (float*)(ws + WS_BQ);
    unsigned int* cand = (unsigned int*)(ws + WS_CAND);
    double* prepPart = (double*)(ws + WS_PREPP);
    double* resC = (double*)(ws + WS_RESC);
    double* resT = (double*)(ws + WS_REST);
    long long* resM = (long long*)(ws + WS_RESM);

    float* out = (float*)d_out;
    float* out_sc = out + (size_t)out_size - 2;
    float* out_z  = out_sc - (size_t)NTOK;

    vq_prep<<<PREP_GRID, 256, 0, stream>>>(c_sum, c_count, c_hi, c_lo, Bn, inv, Bq, prepPart);
    vq_scan<<<SCAN_GRID, SCAN_BLK, 0, stream>>>(vecs, c_hi, c_lo, Bn, cand);
    vq_rescore<<<RES_GRID, 256, 0, stream>>>(vecs, c_sum, c_count, lmask, inv, Bq,
                                             cand, resC, resT, resM, out, out_z);
    vq_final<<<1, 256, 0, stream>>>(prepPart, resC, resT, resM, out_sc);
}